// Round 3
// baseline (1101.412 us; speedup 1.0000x reference)
//
#include <hip/hip_runtime.h>
#include <hip/hip_bf16.h>
#include <stdint.h>

using bf16 = __hip_bfloat16;
using bf16x8 = __attribute__((ext_vector_type(8))) short;   // 8 bf16 = 4 VGPRs
using f32x4  = __attribute__((ext_vector_type(4))) float;

#define AS1 __attribute__((address_space(1)))
#define AS3 __attribute__((address_space(3)))

__device__ __forceinline__ void async_ld16(const void* g, void* l) {
    __builtin_amdgcn_global_load_lds((const AS1 void*)g, (AS3 void*)l, 16, 0, 0);
}

__device__ __forceinline__ f32x4 mfma_bf16(bf16x8 a, bf16x8 b, f32x4 c) {
    return __builtin_amdgcn_mfma_f32_16x16x32_bf16(a, b, c, 0, 0, 0);
}

// safe exp: clamp arg so no lowering of __expf can overflow/NaN
__device__ __forceinline__ float sexp(float x) {
    return __expf(fmaxf(x, -80.0f));
}

// ---------------------------------------------------------------------------
// Stage one 128x32 tile into bf16 LDS.
// SRCF32: global f32 -> VGPR -> cvt -> ds_write_b128 (bf16).
// else:   bf16 source via global_load_lds width=16 (m97 path).
// ---------------------------------------------------------------------------
template<bool SRCF32>
__device__ __forceinline__ void stage_tile(const void* __restrict__ src,
                                           bf16* __restrict__ s,
                                           int row0, int K, int k0, int tid) {
    if constexpr (SRCF32) {
        const float* g = (const float*)src;
        #pragma unroll
        for (int i = 0; i < 2; ++i) {
            int u = tid + 256 * i;                 // 512 units of 8 f32
            int row = u >> 2, c8 = (u & 3) * 8;
            const float* p = g + (size_t)(row0 + row) * K + k0 + c8;
            float4 lo = *(const float4*)p;
            float4 hi = *(const float4*)(p + 4);
            bf16 t8[8] = {__float2bfloat16(lo.x), __float2bfloat16(lo.y),
                          __float2bfloat16(lo.z), __float2bfloat16(lo.w),
                          __float2bfloat16(hi.x), __float2bfloat16(hi.y),
                          __float2bfloat16(hi.z), __float2bfloat16(hi.w)};
            *(bf16x8*)&s[row * 32 + c8] = *(const bf16x8*)t8;
        }
    } else {
        const bf16* g = (const bf16*)src;
        const int wave = tid >> 6, lane = tid & 63;
        const int c0 = wave * 64 + lane;           // 512 chunks of 16 B
        const int r0 = c0 >> 2, cb0 = (c0 & 3) * 16;
        const int c1 = 256 + c0;
        const int r1 = c1 >> 2, cb1 = (c1 & 3) * 16;
        async_ld16((const char*)(g + (size_t)(row0 + r0) * K + k0) + cb0,
                   (char*)s + wave * 1024);
        async_ld16((const char*)(g + (size_t)(row0 + r1) * K + k0) + cb1,
                   (char*)s + 4096 + wave * 1024);
    }
}

// ---------------------------------------------------------------------------
// C = A[M,K] @ B[N,K]^T, MFMA bf16 compute. A/B may be f32 (converted during
// staging) or bf16. C written as f32 (CF32) or bf16. TRANSC: C[n*M+m].
// 128x128 tile, BK=32, 4 waves 2x2, 64x64/wave. M,N mult of 128, K of 32.
// ---------------------------------------------------------------------------
template<bool AF32, bool BF32, bool CF32, bool TRANSC>
__global__ __launch_bounds__(256) void gemm_bt(const void* __restrict__ A,
                                               const void* __restrict__ B,
                                               void* __restrict__ C,
                                               int M, int N, int K) {
    __shared__ bf16 sA[128 * 32];
    __shared__ bf16 sB[128 * 32];
    const int tid  = threadIdx.x;
    const int lane = tid & 63;
    const int wave = tid >> 6;
    const int m0 = blockIdx.y * 128;
    const int n0 = blockIdx.x * 128;
    const int mrow = (wave >> 1) * 64;
    const int ncol = (wave & 1) * 64;

    f32x4 acc[4][4] = {};

    for (int k0 = 0; k0 < K; k0 += 32) {
        __syncthreads();
        stage_tile<AF32>(A, sA, m0, K, k0, tid);
        stage_tile<BF32>(B, sB, n0, K, k0, tid);
        __syncthreads();

        bf16x8 af[4], bfr[4];
        #pragma unroll
        for (int i = 0; i < 4; ++i)
            af[i] = *(const bf16x8*)&sA[(mrow + i * 16 + (lane & 15)) * 32 + (lane >> 4) * 8];
        #pragma unroll
        for (int j = 0; j < 4; ++j)
            bfr[j] = *(const bf16x8*)&sB[(ncol + j * 16 + (lane & 15)) * 32 + (lane >> 4) * 8];
        #pragma unroll
        for (int i = 0; i < 4; ++i)
            #pragma unroll
            for (int j = 0; j < 4; ++j)
                acc[i][j] = mfma_bf16(af[i], bfr[j], acc[i][j]);
    }

    // epilogue: C/D layout row=(lane>>4)*4+r, col=lane&15 (m89/m91-verified)
    #pragma unroll
    for (int i = 0; i < 4; ++i)
        #pragma unroll
        for (int j = 0; j < 4; ++j)
            #pragma unroll
            for (int r = 0; r < 4; ++r) {
                int row = m0 + mrow + i * 16 + (lane >> 4) * 4 + r;
                int col = n0 + ncol + j * 16 + (lane & 15);
                size_t idx = TRANSC ? (size_t)col * M + row : (size_t)row * N + col;
                if constexpr (CF32) ((float*)C)[idx] = acc[i][j][r];
                else                ((bf16*)C)[idx] = __float2bfloat16(acc[i][j][r]);
            }
}

// ---------------------------------------------------------------------------
// RoPE in-place on bf16 X[T, n_heads*128]; cos/sin are f32 [T,64].
// ---------------------------------------------------------------------------
__global__ __launch_bounds__(256) void rope_k(bf16* __restrict__ X,
                                              const float* __restrict__ cosp,
                                              const float* __restrict__ sinp,
                                              int n_heads,
                                              const int* __restrict__ spp) {
    int idx = blockIdx.x * blockDim.x + threadIdx.x;
    int d = idx & 63;
    int h = (idx >> 6) % n_heads;
    int t = idx / (64 * n_heads);
    int sp = *spp;
    float c = cosp[(size_t)(t + sp) * 64 + d];
    float s = sinp[(size_t)(t + sp) * 64 + d];
    bf16* row = X + (size_t)t * n_heads * 128 + h * 128;
    float x1 = __bfloat162float(row[d]);
    float x2 = __bfloat162float(row[64 + d]);
    row[d]      = __float2bfloat16(x1 * c - x2 * s);
    row[64 + d] = __float2bfloat16(x2 * c + x1 * s);
}

// ---------------------------------------------------------------------------
// Flash attention, causal, T=2048, D=128, 32 Q heads, 8 KV heads (GQA 4:1).
// Grid: (qtile 0..31, head 0..31). Block: 256 thr = 4 waves, 16 Q rows/wave.
// Q[T,4096], K[T,1024], VT[1024,T] (bf16), Y[T,4096] bf16 out.
// ---------------------------------------------------------------------------
#define NEG_SENT (-1.0e9f)
__global__ __launch_bounds__(256) void attn_k(const bf16* __restrict__ Q,
                                              const bf16* __restrict__ K,
                                              const bf16* __restrict__ VT,
                                              bf16* __restrict__ Y) {
    constexpr int SKS = 136;  // 128 + 8 pad (bf16 elems)
    constexpr int SVS = 72;   // 64 + 8 pad
    __shared__ bf16 sK[64 * SKS];
    __shared__ bf16 sVT[128 * SVS];
    __shared__ bf16 sP[4][16 * SVS];

    const int tid  = threadIdx.x;
    const int lane = tid & 63;
    const int wave = tid >> 6;
    const int qtile = blockIdx.x;
    const int head  = blockIdx.y;
    const int g     = head >> 2;
    const int qrow0 = qtile * 64 + wave * 16;

    // preload Q A-frags: A[m=lane&15][k=(lane>>4)*8+j], 4 chunks of K=32
    bf16x8 qf[4];
    {
        const bf16* qbase = Q + (size_t)(qrow0 + (lane & 15)) * 4096 + head * 128;
        #pragma unroll
        for (int kk = 0; kk < 4; ++kk)
            qf[kk] = *(const bf16x8*)(qbase + kk * 32 + (lane >> 4) * 8);
    }

    float m_i[4], l_i[4];
    #pragma unroll
    for (int r = 0; r < 4; ++r) { m_i[r] = NEG_SENT; l_i[r] = 0.f; }
    f32x4 o[8] = {};
    const float scale = 0.08838834764831845f;  // 1/sqrt(128)

    for (int kt = 0; kt <= qtile; ++kt) {
        const int kt0 = kt * 64;
        __syncthreads();
        #pragma unroll
        for (int i = 0; i < 4; ++i) {
            int c = i * 256 + tid;
            {
                int row = c >> 4, ch = c & 15;
                *(uint4*)&sK[row * SKS + ch * 8] =
                    *(const uint4*)(K + (size_t)(kt0 + row) * 1024 + g * 128 + ch * 8);
            }
            {
                int row = c >> 3, ch = c & 7;
                *(uint4*)&sVT[row * SVS + ch * 8] =
                    *(const uint4*)(VT + (size_t)(g * 128 + row) * 2048 + kt0 + ch * 8);
            }
        }
        __syncthreads();

        // S = Q K^T
        f32x4 s[4];
        #pragma unroll
        for (int j = 0; j < 4; ++j) {
            f32x4 a = {};
            #pragma unroll
            for (int kk = 0; kk < 4; ++kk) {
                bf16x8 kfrag = *(const bf16x8*)&sK[(j * 16 + (lane & 15)) * SKS +
                                                   kk * 32 + (lane >> 4) * 8];
                a = mfma_bf16(qf[kk], kfrag, a);
            }
            s[j] = a;
        }

        // scale + causal mask
        #pragma unroll
        for (int j = 0; j < 4; ++j) {
            int tk = kt0 + j * 16 + (lane & 15);
            #pragma unroll
            for (int r = 0; r < 4; ++r) {
                int tq = qrow0 + (lane >> 4) * 4 + r;
                float v = s[j][r] * scale;
                s[j][r] = (tk > tq) ? NEG_SENT : v;
            }
        }

        // online softmax per row (rows live in fixed 16-lane groups)
        #pragma unroll
        for (int r = 0; r < 4; ++r) {
            float mx = fmaxf(fmaxf(s[0][r], s[1][r]), fmaxf(s[2][r], s[3][r]));
            #pragma unroll
            for (int d = 1; d < 16; d <<= 1) mx = fmaxf(mx, __shfl_xor(mx, d));
            float mn = fmaxf(m_i[r], mx);
            float alpha = sexp(m_i[r] - mn);
            m_i[r] = mn;
            float rs = 0.f;
            #pragma unroll
            for (int j = 0; j < 4; ++j) {
                float pv = sexp(s[j][r] - mn);
                s[j][r] = pv;
                rs += pv;
            }
            #pragma unroll
            for (int d = 1; d < 16; d <<= 1) rs += __shfl_xor(rs, d);
            l_i[r] = l_i[r] * alpha + rs;
            #pragma unroll
            for (int j2 = 0; j2 < 8; ++j2) o[j2][r] *= alpha;
        }

        // P (C-layout) -> LDS -> A-layout bf16
        bf16* sPw = sP[wave];
        #pragma unroll
        for (int j = 0; j < 4; ++j)
            #pragma unroll
            for (int r = 0; r < 4; ++r)
                sPw[((lane >> 4) * 4 + r) * SVS + j * 16 + (lane & 15)] =
                    __float2bfloat16(s[j][r]);
        __asm__ volatile("s_waitcnt lgkmcnt(0)" ::: "memory");

        // O += P @ V
        #pragma unroll
        for (int kk2 = 0; kk2 < 2; ++kk2) {
            bf16x8 pf = *(const bf16x8*)&sPw[(lane & 15) * SVS + kk2 * 32 + (lane >> 4) * 8];
            #pragma unroll
            for (int j2 = 0; j2 < 8; ++j2) {
                bf16x8 vf = *(const bf16x8*)&sVT[(j2 * 16 + (lane & 15)) * SVS +
                                                 kk2 * 32 + (lane >> 4) * 8];
                o[j2] = mfma_bf16(pf, vf, o[j2]);
            }
        }
    }

    // epilogue: Y[t, head*128 + d] = O / l
    #pragma unroll
    for (int j2 = 0; j2 < 8; ++j2)
        #pragma unroll
        for (int r = 0; r < 4; ++r) {
            int t   = qrow0 + (lane >> 4) * 4 + r;
            int col = head * 128 + j2 * 16 + (lane & 15);
            Y[(size_t)t * 4096 + col] = __float2bfloat16(o[j2][r] / l_i[r]);
        }
}

// ---------------------------------------------------------------------------
extern "C" void kernel_launch(void* const* d_in, const int* in_sizes, int n_in,
                              void* d_out, int out_size, void* d_ws, size_t ws_size,
                              hipStream_t stream) {
    const float* x    = (const float*)d_in[0];
    const float* cosp = (const float*)d_in[1];
    const float* sinp = (const float*)d_in[2];
    const float* wq   = (const float*)d_in[3];
    const float* wk   = (const float*)d_in[4];
    const float* wv   = (const float*)d_in[5];
    const float* wo   = (const float*)d_in[6];
    const int*   sp   = (const int*)d_in[7];
    float* out = (float*)d_out;

    char* ws = (char*)d_ws;
    // Q (bf16, 16 MB) lives in d_out's 32 MB f32 buffer; dead before final GEMM.
    bf16* Qb = (bf16*)d_out;
    bf16* Kb = (bf16*)(ws);                    // 2048*1024 bf16 =  4 MB
    bf16* VT = (bf16*)(ws + (4u << 20));       // 1024*2048 bf16 =  4 MB
    bf16* Yb = (bf16*)(ws + (8u << 20));       // 2048*4096 bf16 = 16 MB

    // projections (f32 in -> bf16 out)
    gemm_bt<true, true, false, false><<<dim3(32, 16), 256, 0, stream>>>(x, wq, Qb, 2048, 4096, 4096);
    gemm_bt<true, true, false, false><<<dim3(8, 16), 256, 0, stream>>>(x, wk, Kb, 2048, 1024, 4096);
    gemm_bt<true, true, false, true ><<<dim3(8, 16), 256, 0, stream>>>(x, wv, VT, 2048, 1024, 4096);

    // rope on Q (32 heads) and K (8 kv heads)
    rope_k<<<dim3(2048 * 32 * 64 / 256), 256, 0, stream>>>(Qb, cosp, sinp, 32, sp);
    rope_k<<<dim3(2048 * 8 * 64 / 256), 256, 0, stream>>>(Kb, cosp, sinp, 8, sp);

    // flash attention -> Yb (bf16)
    attn_k<<<dim3(32, 32), 256, 0, stream>>>(Qb, Kb, VT, Yb);

    // output projection (bf16 A, f32 B -> f32 out)
    gemm_bt<false, true, true, false><<<dim3(32, 16), 256, 0, stream>>>(Yb, wo, out, 2048, 4096, 4096);
}

// Round 4
// 618.999 us; speedup vs baseline: 1.7793x; 1.7793x over previous
//
#include <hip/hip_runtime.h>
#include <hip/hip_bf16.h>
#include <stdint.h>

using bf16 = __hip_bfloat16;
using bf16x8 = __attribute__((ext_vector_type(8))) short;   // 8 bf16 = 4 VGPRs
using f32x4  = __attribute__((ext_vector_type(4))) float;

#define AS1 __attribute__((address_space(1)))
#define AS3 __attribute__((address_space(3)))

__device__ __forceinline__ void async_ld16(const void* g, void* l) {
    __builtin_amdgcn_global_load_lds((const AS1 void*)g, (AS3 void*)l, 16, 0, 0);
}

__device__ __forceinline__ f32x4 mfma_bf16(bf16x8 a, bf16x8 b, f32x4 c) {
    return __builtin_amdgcn_mfma_f32_16x16x32_bf16(a, b, c, 0, 0, 0);
}

__device__ __forceinline__ float sexp(float x) {
    return __expf(fmaxf(x, -80.0f));
}

// ---------------------------------------------------------------------------
// f32 -> bf16 elementwise convert, 8 elems/thread, grid-stride.
// ---------------------------------------------------------------------------
__global__ __launch_bounds__(256) void cvt_f32_bf16(const float* __restrict__ src,
                                                    bf16* __restrict__ dst, int n8) {
    int stride = gridDim.x * blockDim.x;
    for (int u = blockIdx.x * blockDim.x + threadIdx.x; u < n8; u += stride) {
        const float* p = src + (size_t)u * 8;
        float4 lo = *(const float4*)p;
        float4 hi = *(const float4*)(p + 4);
        bf16 t8[8] = {__float2bfloat16(lo.x), __float2bfloat16(lo.y),
                      __float2bfloat16(lo.z), __float2bfloat16(lo.w),
                      __float2bfloat16(hi.x), __float2bfloat16(hi.y),
                      __float2bfloat16(hi.z), __float2bfloat16(hi.w)};
        *(bf16x8*)&dst[(size_t)u * 8] = *(const bf16x8*)t8;
    }
}

// ---------------------------------------------------------------------------
// Stage one 128x32 tile into bf16 LDS.
// SRCF32: f32 -> VGPR -> cvt -> ds_write_b128. else: async global_load_lds x16.
// ---------------------------------------------------------------------------
template<bool SRCF32>
__device__ __forceinline__ void stage_tile(const void* __restrict__ src,
                                           bf16* __restrict__ s,
                                           int row0, int K, int k0, int tid) {
    if constexpr (SRCF32) {
        const float* g = (const float*)src;
        #pragma unroll
        for (int i = 0; i < 2; ++i) {
            int u = tid + 256 * i;
            int row = u >> 2, c8 = (u & 3) * 8;
            const float* p = g + (size_t)(row0 + row) * K + k0 + c8;
            float4 lo = *(const float4*)p;
            float4 hi = *(const float4*)(p + 4);
            bf16 t8[8] = {__float2bfloat16(lo.x), __float2bfloat16(lo.y),
                          __float2bfloat16(lo.z), __float2bfloat16(lo.w),
                          __float2bfloat16(hi.x), __float2bfloat16(hi.y),
                          __float2bfloat16(hi.z), __float2bfloat16(hi.w)};
            *(bf16x8*)&s[row * 32 + c8] = *(const bf16x8*)t8;
        }
    } else {
        const bf16* g = (const bf16*)src;
        const int wave = tid >> 6, lane = tid & 63;
        const int c0 = wave * 64 + lane;
        const int r0 = c0 >> 2, cb0 = (c0 & 3) * 16;
        const int c1 = 256 + c0;
        const int r1 = c1 >> 2, cb1 = (c1 & 3) * 16;
        async_ld16((const char*)(g + (size_t)(row0 + r0) * K + k0) + cb0,
                   (char*)s + wave * 1024);
        async_ld16((const char*)(g + (size_t)(row0 + r1) * K + k0) + cb1,
                   (char*)s + 4096 + wave * 1024);
    }
}

// ---------------------------------------------------------------------------
// C = A[M,K] @ B[N,K]^T, bf16 MFMA compute, 128x128 tile, BK=32, 4 waves.
// MODE 0: C bf16 row-major. MODE 1: C bf16 transposed (C[n*M+m]).
// MODE 2: QKV route -- col<4096 -> Qp[row*4096+col], col<5120 -> Kp[row*1024+..],
//         else Vp[(col-5120)*2048+row] (V transposed). MODE 3: C f32 row-major.
// ---------------------------------------------------------------------------
template<bool AF32, bool BF32, int MODE>
__global__ __launch_bounds__(256) void gemm_bt(const void* __restrict__ A,
                                               const void* __restrict__ B,
                                               void* __restrict__ C,
                                               bf16* __restrict__ Qp,
                                               bf16* __restrict__ Kp,
                                               bf16* __restrict__ Vp,
                                               int M, int N, int K) {
    __shared__ bf16 sA[128 * 32];
    __shared__ bf16 sB[128 * 32];
    const int tid  = threadIdx.x;
    const int lane = tid & 63;
    const int wave = tid >> 6;
    const int m0 = blockIdx.y * 128;
    const int n0 = blockIdx.x * 128;
    const int mrow = (wave >> 1) * 64;
    const int ncol = (wave & 1) * 64;

    f32x4 acc[4][4] = {};

    for (int k0 = 0; k0 < K; k0 += 32) {
        __syncthreads();
        stage_tile<AF32>(A, sA, m0, K, k0, tid);
        stage_tile<BF32>(B, sB, n0, K, k0, tid);
        __syncthreads();

        bf16x8 af[4], bfr[4];
        #pragma unroll
        for (int i = 0; i < 4; ++i)
            af[i] = *(const bf16x8*)&sA[(mrow + i * 16 + (lane & 15)) * 32 + (lane >> 4) * 8];
        #pragma unroll
        for (int j = 0; j < 4; ++j)
            bfr[j] = *(const bf16x8*)&sB[(ncol + j * 16 + (lane & 15)) * 32 + (lane >> 4) * 8];
        #pragma unroll
        for (int i = 0; i < 4; ++i)
            #pragma unroll
            for (int j = 0; j < 4; ++j)
                acc[i][j] = mfma_bf16(af[i], bfr[j], acc[i][j]);
    }

    // epilogue: C/D layout row=(lane>>4)*4+r, col=lane&15 (m89/m91-verified)
    #pragma unroll
    for (int i = 0; i < 4; ++i)
        #pragma unroll
        for (int j = 0; j < 4; ++j)
            #pragma unroll
            for (int r = 0; r < 4; ++r) {
                int row = m0 + mrow + i * 16 + (lane >> 4) * 4 + r;
                int col = n0 + ncol + j * 16 + (lane & 15);
                float fv = acc[i][j][r];
                if constexpr (MODE == 0) {
                    ((bf16*)C)[(size_t)row * N + col] = __float2bfloat16(fv);
                } else if constexpr (MODE == 1) {
                    ((bf16*)C)[(size_t)col * M + row] = __float2bfloat16(fv);
                } else if constexpr (MODE == 2) {
                    bf16 v = __float2bfloat16(fv);
                    if (col < 4096)      Qp[(size_t)row * 4096 + col] = v;
                    else if (col < 5120) Kp[(size_t)row * 1024 + (col - 4096)] = v;
                    else                 Vp[(size_t)(col - 5120) * 2048 + row] = v;
                } else {
                    ((float*)C)[(size_t)row * N + col] = fv;
                }
            }
}

// ---------------------------------------------------------------------------
// RoPE in-place on bf16 X[T, n_heads*128]; cos/sin f32 [T,64].
// ---------------------------------------------------------------------------
__global__ __launch_bounds__(256) void rope_k(bf16* __restrict__ X,
                                              const float* __restrict__ cosp,
                                              const float* __restrict__ sinp,
                                              int n_heads,
                                              const int* __restrict__ spp) {
    int idx = blockIdx.x * blockDim.x + threadIdx.x;
    int d = idx & 63;
    int h = (idx >> 6) % n_heads;
    int t = idx / (64 * n_heads);
    int sp = *spp;
    float c = cosp[(size_t)(t + sp) * 64 + d];
    float s = sinp[(size_t)(t + sp) * 64 + d];
    bf16* row = X + (size_t)t * n_heads * 128 + h * 128;
    float x1 = __bfloat162float(row[d]);
    float x2 = __bfloat162float(row[64 + d]);
    row[d]      = __float2bfloat16(x1 * c - x2 * s);
    row[64 + d] = __float2bfloat16(x2 * c + x1 * s);
}

// ---------------------------------------------------------------------------
// Flash attention, causal, T=2048, D=128, 32 Q heads, 8 KV heads (GQA 4:1).
// 1D grid 1024 blocks; longest-first: qtile = 31 - (bx>>5), head = bx&31.
// Block: 256 thr = 4 waves, 16 Q rows/wave (64-row Q tile, 64-key K tiles).
// ---------------------------------------------------------------------------
#define NEG_SENT (-1.0e9f)
__global__ __launch_bounds__(256) void attn_k(const bf16* __restrict__ Q,
                                              const bf16* __restrict__ K,
                                              const bf16* __restrict__ VT,
                                              bf16* __restrict__ Y) {
    constexpr int SKS = 136;
    constexpr int SVS = 72;
    __shared__ bf16 sK[64 * SKS];
    __shared__ bf16 sVT[128 * SVS];
    __shared__ bf16 sP[4][16 * SVS];

    const int tid  = threadIdx.x;
    const int lane = tid & 63;
    const int wave = tid >> 6;
    const int qtile = 31 - (blockIdx.x >> 5);   // longest blocks first
    const int head  = blockIdx.x & 31;
    const int g     = head >> 2;
    const int qrow0 = qtile * 64 + wave * 16;

    bf16x8 qf[4];
    {
        const bf16* qbase = Q + (size_t)(qrow0 + (lane & 15)) * 4096 + head * 128;
        #pragma unroll
        for (int kk = 0; kk < 4; ++kk)
            qf[kk] = *(const bf16x8*)(qbase + kk * 32 + (lane >> 4) * 8);
    }

    float m_i[4], l_i[4];
    #pragma unroll
    for (int r = 0; r < 4; ++r) { m_i[r] = NEG_SENT; l_i[r] = 0.f; }
    f32x4 o[8] = {};
    const float scale = 0.08838834764831845f;

    for (int kt = 0; kt <= qtile; ++kt) {
        const int kt0 = kt * 64;
        __syncthreads();
        #pragma unroll
        for (int i = 0; i < 4; ++i) {
            int c = i * 256 + tid;
            {
                int row = c >> 4, ch = c & 15;
                *(uint4*)&sK[row * SKS + ch * 8] =
                    *(const uint4*)(K + (size_t)(kt0 + row) * 1024 + g * 128 + ch * 8);
            }
            {
                int row = c >> 3, ch = c & 7;
                *(uint4*)&sVT[row * SVS + ch * 8] =
                    *(const uint4*)(VT + (size_t)(g * 128 + row) * 2048 + kt0 + ch * 8);
            }
        }
        __syncthreads();

        f32x4 s[4];
        #pragma unroll
        for (int j = 0; j < 4; ++j) {
            f32x4 a = {};
            #pragma unroll
            for (int kk = 0; kk < 4; ++kk) {
                bf16x8 kfrag = *(const bf16x8*)&sK[(j * 16 + (lane & 15)) * SKS +
                                                   kk * 32 + (lane >> 4) * 8];
                a = mfma_bf16(qf[kk], kfrag, a);
            }
            s[j] = a;
        }

        #pragma unroll
        for (int j = 0; j < 4; ++j) {
            int tk = kt0 + j * 16 + (lane & 15);
            #pragma unroll
            for (int r = 0; r < 4; ++r) {
                int tq = qrow0 + (lane >> 4) * 4 + r;
                float v = s[j][r] * scale;
                s[j][r] = (tk > tq) ? NEG_SENT : v;
            }
        }

        #pragma unroll
        for (int r = 0; r < 4; ++r) {
            float mx = fmaxf(fmaxf(s[0][r], s[1][r]), fmaxf(s[2][r], s[3][r]));
            #pragma unroll
            for (int d = 1; d < 16; d <<= 1) mx = fmaxf(mx, __shfl_xor(mx, d));
            float mn = fmaxf(m_i[r], mx);
            float alpha = sexp(m_i[r] - mn);
            m_i[r] = mn;
            float rs = 0.f;
            #pragma unroll
            for (int j = 0; j < 4; ++j) {
                float pv = sexp(s[j][r] - mn);
                s[j][r] = pv;
                rs += pv;
            }
            #pragma unroll
            for (int d = 1; d < 16; d <<= 1) rs += __shfl_xor(rs, d);
            l_i[r] = l_i[r] * alpha + rs;
            #pragma unroll
            for (int j2 = 0; j2 < 8; ++j2) o[j2][r] *= alpha;
        }

        bf16* sPw = sP[wave];
        #pragma unroll
        for (int j = 0; j < 4; ++j)
            #pragma unroll
            for (int r = 0; r < 4; ++r)
                sPw[((lane >> 4) * 4 + r) * SVS + j * 16 + (lane & 15)] =
                    __float2bfloat16(s[j][r]);
        __asm__ volatile("s_waitcnt lgkmcnt(0)" ::: "memory");

        #pragma unroll
        for (int kk2 = 0; kk2 < 2; ++kk2) {
            bf16x8 pf = *(const bf16x8*)&sPw[(lane & 15) * SVS + kk2 * 32 + (lane >> 4) * 8];
            #pragma unroll
            for (int j2 = 0; j2 < 8; ++j2) {
                bf16x8 vf = *(const bf16x8*)&sVT[(j2 * 16 + (lane & 15)) * SVS +
                                                 kk2 * 32 + (lane >> 4) * 8];
                o[j2] = mfma_bf16(pf, vf, o[j2]);
            }
        }
    }

    #pragma unroll
    for (int j2 = 0; j2 < 8; ++j2)
        #pragma unroll
        for (int r = 0; r < 4; ++r) {
            int t   = qrow0 + (lane >> 4) * 4 + r;
            int col = head * 128 + j2 * 16 + (lane & 15);
            Y[(size_t)t * 4096 + col] = __float2bfloat16(o[j2][r] / l_i[r]);
        }
}

// ---------------------------------------------------------------------------
extern "C" void kernel_launch(void* const* d_in, const int* in_sizes, int n_in,
                              void* d_out, int out_size, void* d_ws, size_t ws_size,
                              hipStream_t stream) {
    const float* x    = (const float*)d_in[0];
    const float* cosp = (const float*)d_in[1];
    const float* sinp = (const float*)d_in[2];
    const float* wq   = (const float*)d_in[3];
    const float* wk   = (const float*)d_in[4];
    const float* wv   = (const float*)d_in[5];
    const float* wo   = (const float*)d_in[6];
    const int*   sp   = (const int*)d_in[7];
    float* out = (float*)d_out;

    char* ws = (char*)d_ws;
    bf16* Qb = (bf16*)d_out;   // 16 MB bf16 in the 32 MB f32 out buffer; dead before final GEMM

    // fast path needs: xb 16 + wqkv/wob 48 + Kb 4 + VT 4 + Yb 16 = 88 MiB
    const size_t NEED = 92274688;
    if (ws_size >= NEED) {
        bf16* xb   = (bf16*)(ws);
        bf16* wqkv = (bf16*)(ws + (16u << 20));   // wq rows 0-4095, wk 4096-5119, wv 5120-6143
        bf16* wob  = wqkv;                         // aliased; converted after QKV GEMM
        bf16* Kb   = (bf16*)(ws + (64u << 20));
        bf16* VT   = (bf16*)(ws + (68u << 20));
        bf16* Yb   = (bf16*)(ws + (72u << 20));

        // converts (f32 -> bf16)
        cvt_f32_bf16<<<dim3(4096), 256, 0, stream>>>(x,  xb,               1048576);
        cvt_f32_bf16<<<dim3(4096), 256, 0, stream>>>(wq, wqkv,             2097152);
        cvt_f32_bf16<<<dim3(2048), 256, 0, stream>>>(wk, wqkv + 16777216,   524288);
        cvt_f32_bf16<<<dim3(2048), 256, 0, stream>>>(wv, wqkv + 20971520,   524288);

        // fused QKV projection: M=2048, N=6144, K=4096 -> 768 blocks (3/CU)
        gemm_bt<false, false, 2><<<dim3(48, 16), 256, 0, stream>>>(
            xb, wqkv, nullptr, Qb, Kb, VT, 2048, 6144, 4096);

        // wo -> bf16 (after QKV GEMM consumed wqkv; same region)
        cvt_f32_bf16<<<dim3(4096), 256, 0, stream>>>(wo, wob, 2097152);

        rope_k<<<dim3(2048 * 32 * 64 / 256), 256, 0, stream>>>(Qb, cosp, sinp, 32, sp);
        rope_k<<<dim3(2048 * 8 * 64 / 256), 256, 0, stream>>>(Kb, cosp, sinp, 8, sp);

        attn_k<<<dim3(1024), 256, 0, stream>>>(Qb, Kb, VT, Yb);

        // output projection: bf16 x bf16 -> f32
        gemm_bt<false, false, 3><<<dim3(32, 16), 256, 0, stream>>>(
            Yb, wob, out, nullptr, nullptr, nullptr, 2048, 4096, 4096);
    } else {
        // fallback: R3 path (convert during staging), needs 24 MiB ws
        bf16* Kb = (bf16*)(ws);
        bf16* VT = (bf16*)(ws + (4u << 20));
        bf16* Yb = (bf16*)(ws + (8u << 20));

        gemm_bt<true, true, 0><<<dim3(32, 16), 256, 0, stream>>>(
            x, wq, Qb, nullptr, nullptr, nullptr, 2048, 4096, 4096);
        gemm_bt<true, true, 0><<<dim3(8, 16), 256, 0, stream>>>(
            x, wk, Kb, nullptr, nullptr, nullptr, 2048, 1024, 4096);
        gemm_bt<true, true, 1><<<dim3(8, 16), 256, 0, stream>>>(
            x, wv, VT, nullptr, nullptr, nullptr, 2048, 1024, 4096);

        rope_k<<<dim3(2048 * 32 * 64 / 256), 256, 0, stream>>>(Qb, cosp, sinp, 32, sp);
        rope_k<<<dim3(2048 * 8 * 64 / 256), 256, 0, stream>>>(Kb, cosp, sinp, 8, sp);

        attn_k<<<dim3(1024), 256, 0, stream>>>(Qb, Kb, VT, Yb);

        gemm_bt<false, true, 3><<<dim3(32, 16), 256, 0, stream>>>(
            Yb, wo, out, nullptr, nullptr, nullptr, 2048, 4096, 4096);
    }
}

// Round 5
// 545.843 us; speedup vs baseline: 2.0178x; 1.1340x over previous
//
#include <hip/hip_runtime.h>
#include <hip/hip_bf16.h>
#include <stdint.h>

using bf16 = __hip_bfloat16;
using bf16x8 = __attribute__((ext_vector_type(8))) short;   // 8 bf16 = 4 VGPRs
using f32x4  = __attribute__((ext_vector_type(4))) float;

#define AS1 __attribute__((address_space(1)))
#define AS3 __attribute__((address_space(3)))

__device__ __forceinline__ void async_ld16(const void* g, void* l) {
    __builtin_amdgcn_global_load_lds((const AS1 void*)g, (AS3 void*)l, 16, 0, 0);
}

__device__ __forceinline__ f32x4 mfma_bf16(bf16x8 a, bf16x8 b, f32x4 c) {
    return __builtin_amdgcn_mfma_f32_16x16x32_bf16(a, b, c, 0, 0, 0);
}

__device__ __forceinline__ float sexp(float x) {
    return __expf(fmaxf(x, -80.0f));
}

// ---- 16-lane-group reductions: DPP row_shr (VALU) + one broadcast swizzle ----
template<int N> __device__ __forceinline__ float dpp_max16(float x) {
    int xi = __builtin_bit_cast(int, x);
    int yi = __builtin_amdgcn_update_dpp(xi, xi, 0x110 | N, 0xf, 0xf, false);
    return fmaxf(x, __builtin_bit_cast(float, yi));
}
template<int N> __device__ __forceinline__ float dpp_add16(float x) {
    int xi = __builtin_bit_cast(int, x);
    int yi = __builtin_amdgcn_update_dpp(0, xi, 0x110 | N, 0xf, 0xf, true);
    return x + __builtin_bit_cast(float, yi);
}
__device__ __forceinline__ float bcast15(float x) {
    // swizzle BitMode: and=0x10, or=0x0F -> every lane reads lane15 of its 16-group
    return __builtin_bit_cast(float,
        __builtin_amdgcn_ds_swizzle(__builtin_bit_cast(int, x), 0x01F0));
}
__device__ __forceinline__ float redmax16(float x) {
    x = dpp_max16<1>(x); x = dpp_max16<2>(x);
    x = dpp_max16<4>(x); x = dpp_max16<8>(x);
    return bcast15(x);
}
__device__ __forceinline__ float redsum16(float x) {
    x = dpp_add16<1>(x); x = dpp_add16<2>(x);
    x = dpp_add16<4>(x); x = dpp_add16<8>(x);
    return bcast15(x);
}

// ---------------------------------------------------------------------------
// Merged f32->bf16 converts: x (1048576 u8), wq (2097152), wk (524288), wv (524288)
// ---------------------------------------------------------------------------
__device__ __forceinline__ void cvt8(const float* p, bf16* d) {
    float4 lo = *(const float4*)p;
    float4 hi = *(const float4*)(p + 4);
    bf16 t8[8] = {__float2bfloat16(lo.x), __float2bfloat16(lo.y),
                  __float2bfloat16(lo.z), __float2bfloat16(lo.w),
                  __float2bfloat16(hi.x), __float2bfloat16(hi.y),
                  __float2bfloat16(hi.z), __float2bfloat16(hi.w)};
    *(bf16x8*)d = *(const bf16x8*)t8;
}

__global__ __launch_bounds__(256) void cvt4_k(const float* __restrict__ x,  bf16* __restrict__ xb,
                                              const float* __restrict__ wq, bf16* __restrict__ wqb,
                                              const float* __restrict__ wk, bf16* __restrict__ wkb,
                                              const float* __restrict__ wv, bf16* __restrict__ wvb) {
    int stride = gridDim.x * blockDim.x;
    for (int u = blockIdx.x * blockDim.x + threadIdx.x; u < 4194304; u += stride) {
        const float* s; bf16* d; size_t off;
        if (u < 1048576)      { s = x;  d = xb;  off = (size_t)u * 8; }
        else if (u < 3145728) { s = wq; d = wqb; off = (size_t)(u - 1048576) * 8; }
        else if (u < 3670016) { s = wk; d = wkb; off = (size_t)(u - 3145728) * 8; }
        else                  { s = wv; d = wvb; off = (size_t)(u - 3670016) * 8; }
        cvt8(s + off, d + off);
    }
}

__global__ __launch_bounds__(256) void cvt_f32_bf16(const float* __restrict__ src,
                                                    bf16* __restrict__ dst, int n8) {
    int stride = gridDim.x * blockDim.x;
    for (int u = blockIdx.x * blockDim.x + threadIdx.x; u < n8; u += stride)
        cvt8(src + (size_t)u * 8, dst + (size_t)u * 8);
}

// ---------------------------------------------------------------------------
// Stage one 128x32 tile into bf16 LDS.
// ---------------------------------------------------------------------------
template<bool SRCF32>
__device__ __forceinline__ void stage_tile(const void* __restrict__ src,
                                           bf16* __restrict__ s,
                                           int row0, int K, int k0, int tid) {
    if constexpr (SRCF32) {
        const float* g = (const float*)src;
        #pragma unroll
        for (int i = 0; i < 2; ++i) {
            int u = tid + 256 * i;
            int row = u >> 2, c8 = (u & 3) * 8;
            cvt8(g + (size_t)(row0 + row) * K + k0 + c8, &s[row * 32 + c8]);
        }
    } else {
        const bf16* g = (const bf16*)src;
        const int wave = tid >> 6, lane = tid & 63;
        const int c0 = wave * 64 + lane;
        const int r0 = c0 >> 2, cb0 = (c0 & 3) * 16;
        const int c1 = 256 + c0;
        const int r1 = c1 >> 2, cb1 = (c1 & 3) * 16;
        async_ld16((const char*)(g + (size_t)(row0 + r0) * K + k0) + cb0,
                   (char*)s + wave * 1024);
        async_ld16((const char*)(g + (size_t)(row0 + r1) * K + k0) + cb1,
                   (char*)s + 4096 + wave * 1024);
    }
}

// ---------------------------------------------------------------------------
// C = A[M,K] @ B[N,K]^T, bf16 MFMA compute, 128x128 tile, BK=32, 4 waves.
// MODE 0: C bf16 row-major. MODE 1: C bf16 transposed. MODE 2: QKV route.
// MODE 3: C f32 row-major.
// ---------------------------------------------------------------------------
template<bool AF32, bool BF32, int MODE>
__global__ __launch_bounds__(256) void gemm_bt(const void* __restrict__ A,
                                               const void* __restrict__ B,
                                               void* __restrict__ C,
                                               bf16* __restrict__ Qp,
                                               bf16* __restrict__ Kp,
                                               bf16* __restrict__ Vp,
                                               int M, int N, int K) {
    __shared__ bf16 sA[128 * 32];
    __shared__ bf16 sB[128 * 32];
    const int tid  = threadIdx.x;
    const int lane = tid & 63;
    const int wave = tid >> 6;
    const int m0 = blockIdx.y * 128;
    const int n0 = blockIdx.x * 128;
    const int mrow = (wave >> 1) * 64;
    const int ncol = (wave & 1) * 64;

    f32x4 acc[4][4] = {};

    for (int k0 = 0; k0 < K; k0 += 32) {
        __syncthreads();
        stage_tile<AF32>(A, sA, m0, K, k0, tid);
        stage_tile<BF32>(B, sB, n0, K, k0, tid);
        __syncthreads();

        bf16x8 af[4], bfr[4];
        #pragma unroll
        for (int i = 0; i < 4; ++i)
            af[i] = *(const bf16x8*)&sA[(mrow + i * 16 + (lane & 15)) * 32 + (lane >> 4) * 8];
        #pragma unroll
        for (int j = 0; j < 4; ++j)
            bfr[j] = *(const bf16x8*)&sB[(ncol + j * 16 + (lane & 15)) * 32 + (lane >> 4) * 8];
        #pragma unroll
        for (int i = 0; i < 4; ++i)
            #pragma unroll
            for (int j = 0; j < 4; ++j)
                acc[i][j] = mfma_bf16(af[i], bfr[j], acc[i][j]);
    }

    #pragma unroll
    for (int i = 0; i < 4; ++i)
        #pragma unroll
        for (int j = 0; j < 4; ++j)
            #pragma unroll
            for (int r = 0; r < 4; ++r) {
                int row = m0 + mrow + i * 16 + (lane >> 4) * 4 + r;
                int col = n0 + ncol + j * 16 + (lane & 15);
                float fv = acc[i][j][r];
                if constexpr (MODE == 0) {
                    ((bf16*)C)[(size_t)row * N + col] = __float2bfloat16(fv);
                } else if constexpr (MODE == 1) {
                    ((bf16*)C)[(size_t)col * M + row] = __float2bfloat16(fv);
                } else if constexpr (MODE == 2) {
                    bf16 v = __float2bfloat16(fv);
                    if (col < 4096)      Qp[(size_t)row * 4096 + col] = v;
                    else if (col < 5120) Kp[(size_t)row * 1024 + (col - 4096)] = v;
                    else                 Vp[(size_t)(col - 5120) * 2048 + row] = v;
                } else {
                    ((float*)C)[(size_t)row * N + col] = fv;
                }
            }
}

// ---------------------------------------------------------------------------
// Merged RoPE: h<32 -> Q head h; h>=32 -> K head h-32. cos/sin f32 [T,64].
// ---------------------------------------------------------------------------
__global__ __launch_bounds__(256) void rope_all(bf16* __restrict__ Q,
                                                bf16* __restrict__ K,
                                                const float* __restrict__ cosp,
                                                const float* __restrict__ sinp,
                                                const int* __restrict__ spp) {
    int idx = blockIdx.x * blockDim.x + threadIdx.x;
    int d = idx & 63;
    int h = (idx >> 6) % 40;
    int t = idx / (64 * 40);
    int sp = *spp;
    float c = cosp[(size_t)(t + sp) * 64 + d];
    float s = sinp[(size_t)(t + sp) * 64 + d];
    bf16* row = (h < 32) ? (Q + (size_t)t * 4096 + h * 128)
                         : (K + (size_t)t * 1024 + (h - 32) * 128);
    float x1 = __bfloat162float(row[d]);
    float x2 = __bfloat162float(row[64 + d]);
    row[d]      = __float2bfloat16(x1 * c - x2 * s);
    row[64 + d] = __float2bfloat16(x2 * c + x1 * s);
}

// ---------------------------------------------------------------------------
// Flash attention, causal, T=2048, D=128, 32 Q heads, 8 KV heads (GQA 4:1).
// 1D grid 1024 blocks, longest-first. 4 waves x 16 Q rows, 64-key tiles.
// LDS 35840 B (P scratch aliased onto sK) -> 4 blocks/CU.
// ---------------------------------------------------------------------------
#define NEG_SENT (-1.0e9f)
__global__ __launch_bounds__(256) void attn_k(const bf16* __restrict__ Q,
                                              const bf16* __restrict__ K,
                                              const bf16* __restrict__ VT,
                                              bf16* __restrict__ Y) {
    constexpr int SKS = 136;
    constexpr int SVS = 72;
    __shared__ bf16 sK[64 * SKS];    // 17408 B; P scratch aliases this
    __shared__ bf16 sVT[128 * SVS];  // 18432 B

    const int tid  = threadIdx.x;
    const int lane = tid & 63;
    const int wave = tid >> 6;
    const int qtile = 31 - (blockIdx.x >> 5);
    const int head  = blockIdx.x & 31;
    const int g     = head >> 2;
    const int qrow0 = qtile * 64 + wave * 16;
    bf16* sPw = sK + wave * 1152;    // 16 rows x SVS stride, within sK block

    bf16x8 qf[4];
    {
        const bf16* qbase = Q + (size_t)(qrow0 + (lane & 15)) * 4096 + head * 128;
        #pragma unroll
        for (int kk = 0; kk < 4; ++kk)
            qf[kk] = *(const bf16x8*)(qbase + kk * 32 + (lane >> 4) * 8);
    }

    float m_i[4], l_i[4];   // l_i = per-lane partial sum (reduced at epilogue)
    #pragma unroll
    for (int r = 0; r < 4; ++r) { m_i[r] = NEG_SENT; l_i[r] = 0.f; }
    f32x4 o[8] = {};
    const float scale = 0.08838834764831845f;

    for (int kt = 0; kt <= qtile; ++kt) {
        const int kt0 = kt * 64;
        __syncthreads();   // prior iter's sK(P)/sVT reads complete
        #pragma unroll
        for (int i = 0; i < 4; ++i) {
            int c = i * 256 + tid;
            {
                int row = c >> 4, ch = c & 15;
                *(uint4*)&sK[row * SKS + ch * 8] =
                    *(const uint4*)(K + (size_t)(kt0 + row) * 1024 + g * 128 + ch * 8);
            }
            {
                int row = c >> 3, ch = c & 7;
                *(uint4*)&sVT[row * SVS + ch * 8] =
                    *(const uint4*)(VT + (size_t)(g * 128 + row) * 2048 + kt0 + ch * 8);
            }
        }
        __syncthreads();   // staging visible

        // S = Q K^T
        f32x4 s[4];
        #pragma unroll
        for (int j = 0; j < 4; ++j) {
            f32x4 a = {};
            #pragma unroll
            for (int kk = 0; kk < 4; ++kk) {
                bf16x8 kfrag = *(const bf16x8*)&sK[(j * 16 + (lane & 15)) * SKS +
                                                   kk * 32 + (lane >> 4) * 8];
                a = mfma_bf16(qf[kk], kfrag, a);
            }
            s[j] = a;
        }

        // scale + causal mask
        #pragma unroll
        for (int j = 0; j < 4; ++j) {
            int tk = kt0 + j * 16 + (lane & 15);
            #pragma unroll
            for (int r = 0; r < 4; ++r) {
                int tq = qrow0 + (lane >> 4) * 4 + r;
                float v = s[j][r] * scale;
                s[j][r] = (tk > tq) ? NEG_SENT : v;
            }
        }

        // online softmax: DPP max reduction; l kept as per-lane partial
        #pragma unroll
        for (int r = 0; r < 4; ++r) {
            float mx = fmaxf(fmaxf(s[0][r], s[1][r]), fmaxf(s[2][r], s[3][r]));
            mx = redmax16(mx);
            float mn = fmaxf(m_i[r], mx);
            float alpha = sexp(m_i[r] - mn);
            m_i[r] = mn;
            float rs = 0.f;
            #pragma unroll
            for (int j = 0; j < 4; ++j) {
                float pv = sexp(s[j][r] - mn);
                s[j][r] = pv;
                rs += pv;
            }
            l_i[r] = l_i[r] * alpha + rs;
            #pragma unroll
            for (int j2 = 0; j2 < 8; ++j2) o[j2][r] *= alpha;
        }

        __syncthreads();   // all waves done reading sK -> safe to write P there

        // P (C-layout) -> LDS -> A-layout bf16
        #pragma unroll
        for (int j = 0; j < 4; ++j)
            #pragma unroll
            for (int r = 0; r < 4; ++r)
                sPw[((lane >> 4) * 4 + r) * SVS + j * 16 + (lane & 15)] =
                    __float2bfloat16(s[j][r]);
        __asm__ volatile("s_waitcnt lgkmcnt(0)" ::: "memory");

        // O += P @ V
        #pragma unroll
        for (int kk2 = 0; kk2 < 2; ++kk2) {
            bf16x8 pf = *(const bf16x8*)&sPw[(lane & 15) * SVS + kk2 * 32 + (lane >> 4) * 8];
            #pragma unroll
            for (int j2 = 0; j2 < 8; ++j2) {
                bf16x8 vf = *(const bf16x8*)&sVT[(j2 * 16 + (lane & 15)) * SVS +
                                                 kk2 * 32 + (lane >> 4) * 8];
                o[j2] = mfma_bf16(pf, vf, o[j2]);
            }
        }
    }

    // epilogue: reduce l partials across the 16-lane group, then normalize
    #pragma unroll
    for (int r = 0; r < 4; ++r) l_i[r] = redsum16(l_i[r]);
    #pragma unroll
    for (int j2 = 0; j2 < 8; ++j2)
        #pragma unroll
        for (int r = 0; r < 4; ++r) {
            int t   = qrow0 + (lane >> 4) * 4 + r;
            int col = head * 128 + j2 * 16 + (lane & 15);
            Y[(size_t)t * 4096 + col] = __float2bfloat16(o[j2][r] / l_i[r]);
        }
}

// ---------------------------------------------------------------------------
extern "C" void kernel_launch(void* const* d_in, const int* in_sizes, int n_in,
                              void* d_out, int out_size, void* d_ws, size_t ws_size,
                              hipStream_t stream) {
    const float* x    = (const float*)d_in[0];
    const float* cosp = (const float*)d_in[1];
    const float* sinp = (const float*)d_in[2];
    const float* wq   = (const float*)d_in[3];
    const float* wk   = (const float*)d_in[4];
    const float* wv   = (const float*)d_in[5];
    const float* wo   = (const float*)d_in[6];
    const int*   sp   = (const int*)d_in[7];
    float* out = (float*)d_out;

    char* ws = (char*)d_ws;
    bf16* Qb = (bf16*)d_out;   // 16 MB bf16 in the 32 MB f32 out buffer

    const size_t NEED = 92274688;   // 88 MiB
    if (ws_size >= NEED) {
        bf16* xb   = (bf16*)(ws);
        bf16* wqkv = (bf16*)(ws + (16u << 20));
        bf16* wob  = wqkv;                     // aliased; converted after QKV GEMM
        bf16* Kb   = (bf16*)(ws + (64u << 20));
        bf16* VT   = (bf16*)(ws + (68u << 20));
        bf16* Yb   = (bf16*)(ws + (72u << 20));

        cvt4_k<<<dim3(4096), 256, 0, stream>>>(x, xb, wq, wqkv,
                                               wk, wqkv + 16777216, wv, wqkv + 20971520);

        gemm_bt<false, false, 2><<<dim3(48, 16), 256, 0, stream>>>(
            xb, wqkv, nullptr, Qb, Kb, VT, 2048, 6144, 4096);

        cvt_f32_bf16<<<dim3(4096), 256, 0, stream>>>(wo, wob, 2097152);

        rope_all<<<dim3(2048 * 40 * 64 / 256), 256, 0, stream>>>(Qb, Kb, cosp, sinp, sp);

        attn_k<<<dim3(1024), 256, 0, stream>>>(Qb, Kb, VT, Yb);

        gemm_bt<false, false, 3><<<dim3(32, 16), 256, 0, stream>>>(
            Yb, wob, out, nullptr, nullptr, nullptr, 2048, 4096, 4096);
    } else {
        bf16* Kb = (bf16*)(ws);
        bf16* VT = (bf16*)(ws + (4u << 20));
        bf16* Yb = (bf16*)(ws + (8u << 20));

        gemm_bt<true, true, 0><<<dim3(32, 16), 256, 0, stream>>>(
            x, wq, Qb, nullptr, nullptr, nullptr, 2048, 4096, 4096);
        gemm_bt<true, true, 0><<<dim3(8, 16), 256, 0, stream>>>(
            x, wk, Kb, nullptr, nullptr, nullptr, 2048, 1024, 4096);
        gemm_bt<true, true, 1><<<dim3(8, 16), 256, 0, stream>>>(
            x, wv, VT, nullptr, nullptr, nullptr, 2048, 1024, 4096);

        rope_all<<<dim3(2048 * 40 * 64 / 256), 256, 0, stream>>>(Qb, Kb, cosp, sinp, sp);

        attn_k<<<dim3(1024), 256, 0, stream>>>(Qb, Kb, VT, Yb);

        gemm_bt<false, true, 3><<<dim3(32, 16), 256, 0, stream>>>(
            Yb, wo, out, nullptr, nullptr, nullptr, 2048, 4096, 4096);
    }
}